// Round 5
// baseline (1005.330 us; speedup 1.0000x reference)
//
#include <hip/hip_runtime.h>
#include <stdint.h>

typedef unsigned short u16;
typedef unsigned int   u32;

#define NNODES 10000
#define NEDGES 20000
#define ETOT   30000
#define NHEADS 12
#define CDIM   768
#define FDIM   768
#define KDIM   9216
#define NGRAPH 64
#define MPAD   10240   // 40*256 row tiles for the 256^2 GEMM; pad rows zeroed, never read
#define NEG_SLOPE 0.2f
#define DMAX   32      // max in-degree incl. self-loop; max of 10000 Poisson(2) ~ 14

typedef __attribute__((ext_vector_type(8))) short short8;
typedef __attribute__((ext_vector_type(4))) float f32x4;

__device__ __forceinline__ u16 f32_bf16(float f) {
  u32 u = __float_as_uint(f);
  u = (u + 0x7FFFu + ((u >> 16) & 1u)) >> 16;
  return (u16)u;
}
__device__ __forceinline__ float bf16_f32(u16 v) {
  return __uint_as_float(((u32)v) << 16);
}

// ---------------- CSR build ----------------
__global__ void k_count(const int* __restrict__ dste, int* __restrict__ counts) {
  int e = blockIdx.x * blockDim.x + threadIdx.x;
  if (e >= ETOT) return;
  int dst;
  if (e < NEDGES) dst = dste[e]; else dst = e - NEDGES;
  atomicAdd(&counts[dst], 1);
}

__global__ void k_scan(const int* __restrict__ counts, int* __restrict__ offs) {
  __shared__ int part[256];
  int t = threadIdx.x;
  const int chunk = 40;
  int beg = t * chunk;
  int end = beg + chunk; if (end > NNODES) end = NNODES;
  int s = 0;
  for (int i = beg; i < end && i < NNODES; i++) s += counts[i];
  part[t] = s;
  __syncthreads();
  for (int d = 1; d < 256; d <<= 1) {
    int v = (t >= d) ? part[t - d] : 0;
    __syncthreads();
    part[t] += v;
    __syncthreads();
  }
  int base = (t == 0) ? 0 : part[t - 1];
  for (int i = beg; i < end && i < NNODES; i++) { offs[i] = base; base += counts[i]; }
  if (t == 255) offs[NNODES] = base;
}

__global__ void k_seed(const int* __restrict__ offs, int* __restrict__ cursor) {
  int n = blockIdx.x * blockDim.x + threadIdx.x;
  if (n < NNODES) cursor[n] = offs[n];
}

__global__ void k_scatter(const int* __restrict__ dste, int* __restrict__ cursor,
                          int* __restrict__ elist) {
  int e = blockIdx.x * blockDim.x + threadIdx.x;
  if (e >= ETOT) return;
  int dst;
  if (e < NEDGES) dst = dste[e]; else dst = e - NEDGES;
  int pos = atomicAdd(&cursor[dst], 1);
  elist[pos] = e;
}

// ------- Ut[o*768+k] = sum_c W[k, h*768+c] * a[h, c] ; 4 waves x 6 o's per block -------
__global__ void k_U(const float* __restrict__ W, const float* __restrict__ a_src,
                    const float* __restrict__ a_dst, float* __restrict__ Ut) {
  int k = blockIdx.x;
  int t = threadIdx.x, w = t >> 6, l = t & 63;
  const float* Wrow = W + (size_t)k * KDIM;
#pragma unroll
  for (int q = 0; q < 6; q++) {
    int o = w * 6 + q;
    int h = (o < 12) ? o : o - 12;
    const float* av = (o < 12) ? (a_src + h * CDIM) : (a_dst + h * CDIM);
    const float* wr = Wrow + h * CDIM;
    float p = 0.f;
    for (int c = l; c < CDIM; c += 64) p += wr[c] * av[c];
#pragma unroll
    for (int d = 32; d > 0; d >>= 1) p += __shfl_down(p, d, 64);
    if (l == 0) Ut[o * FDIM + k] = p;
  }
}

// ---- sd: Ut staged in LDS once per block; 20 nodes/block. Also writes xbf (GEMM A). ----
__global__ void k_sd(const float* __restrict__ xin, const float* __restrict__ Ut,
                     float* __restrict__ sd, u16* __restrict__ xbf) {
  __shared__ float UtS[24 * FDIM];   // 73728 B
  int t = threadIdx.x, w = t >> 6, l = t & 63;
  const float4* U4 = (const float4*)Ut;
  float4* S4 = (float4*)UtS;
  for (int i = t; i < 24 * FDIM / 4; i += 256) S4[i] = U4[i];
  __syncthreads();
#pragma unroll
  for (int rep = 0; rep < 5; rep++) {
    int n = blockIdx.x * 20 + w * 5 + rep;
    if (n >= NNODES) continue;
    const float* xr = xin + (size_t)n * FDIM;
    float4 x0 = *(const float4*)(xr + 4 * l);
    float4 x1 = *(const float4*)(xr + 4 * l + 256);
    float4 x2 = *(const float4*)(xr + 4 * l + 512);
    // bf16 copy for the GEMM A operand
    u16* xb = xbf + (size_t)n * FDIM + 4 * l;
    ushort4 p0, p1, p2;
    p0.x = f32_bf16(x0.x); p0.y = f32_bf16(x0.y); p0.z = f32_bf16(x0.z); p0.w = f32_bf16(x0.w);
    p1.x = f32_bf16(x1.x); p1.y = f32_bf16(x1.y); p1.z = f32_bf16(x1.z); p1.w = f32_bf16(x1.w);
    p2.x = f32_bf16(x2.x); p2.y = f32_bf16(x2.y); p2.z = f32_bf16(x2.z); p2.w = f32_bf16(x2.w);
    *(ushort4*)xb = p0;
    *(ushort4*)(xb + 256) = p1;
    *(ushort4*)(xb + 512) = p2;
#pragma unroll
    for (int o = 0; o < 24; o++) {
      const float4* up = (const float4*)(UtS + o * FDIM + 4 * l);
      float4 u0 = up[0];
      float4 u1 = up[64];
      float4 u2 = up[128];
      float a = x0.x * u0.x + x0.y * u0.y + x0.z * u0.z + x0.w * u0.w
              + x1.x * u1.x + x1.y * u1.y + x1.z * u1.z + x1.w * u1.w
              + x2.x * u2.x + x2.y * u2.y + x2.z * u2.z + x2.w * u2.w;
#pragma unroll
      for (int d = 32; d > 0; d >>= 1) a += __shfl_xor(a, d, 64);
      if (l == 0) sd[n * 24 + o] = a;
    }
  }
}

// -------- Bt[j, k] = bf16(W[k, j])  — straight transpose, row length 768 --------
__global__ void k_trans(const float* __restrict__ W, u16* __restrict__ Bt) {
  int kt = blockIdx.x * 32, jt = blockIdx.y * 32;
  int tx = threadIdx.x, ty = threadIdx.y;  // 32, 8
  __shared__ float tile[32][33];
#pragma unroll
  for (int r = 0; r < 4; r++)
    tile[ty + 8 * r][tx] = W[(size_t)(kt + ty + 8 * r) * KDIM + jt + tx];
  __syncthreads();
#pragma unroll
  for (int r = 0; r < 4; r++)
    Bt[(size_t)(jt + ty + 8 * r) * FDIM + kt + tx] = f32_bf16(tile[tx][ty + 8 * r]);
}

// ============================================================================
// GEMM: Hbig[MPAD,9216] bf16 = xbf[MPAD,768] @ Bt[9216,768]^T.
// 256x256 tile, BK=64, 512 threads (2x4 waves, 128x64/wave), 8-phase schedule
// (T2 swizzle / T3+T4 counted vmcnt / T5 setprio — r3: conflicts measured 0).
//
// r3 POST-MORTEM: FETCH_SIZE 292 MB vs 30 MB of inputs (~10x re-fetch);
// hbm_bytes/dur matches the old kernel's bandwidth curve -> k_gemm is
// HBM-TRAFFIC-bound, not schedule-bound. Two fixes, one theory:
//  (1) NONTEMPORAL C stores: the 188 MB write-once stream must not evict
//      A/B (30 MB total) from L2/L3.
//  (2) L2-CHUNKED XCD SWIZZLE: XCD x owns rows [5x,5x+5); traverse its
//      5x36 stripe in 5-row x 6-col chunks, column-major inside a chunk.
//      Concurrent working set/XCD = 5 A-panels (2.0 MB) + 6 B-panels
//      (2.3 MB) ~ 4 MiB L2; all XCDs stream the same B-chunk sequence in
//      phase -> L3 serves B cross-XCD. Bijective: 40=8*5 rows, 36=6*6 cols.
//
// vmcnt ledger (audited r1, unchanged): after prologue 4 in flight; each
// tile issues 8 (p0:(s+1)B1, p1:(s+1)A1, p2:(s+2)B0, p3:(s+2)A0), retires 8
// at tile-end vmcnt(4) => tile s+1 fully landed before its first ds_read;
// following s_barrier extends cross-wave. Tail: s=10 vmcnt(0), s=11 none.
// Overwrite-safety: stB(P,0,s+2)@p2 / stA(P,0,s+2)@p3 are issued after the
// barrier that follows the last ds_read of that region (see r1 audit).
// ============================================================================
#define GLL16(G, L) __builtin_amdgcn_global_load_lds( \
  (const __attribute__((address_space(1))) void*)(G), \
  (__attribute__((address_space(3))) void*)(L), 16, 0, 0)

__global__ __launch_bounds__(512, 2) void k_gemm(const u16* __restrict__ A,
    const u16* __restrict__ B, u16* __restrict__ C) {
  __shared__ __align__(16) u16 As[2][256 * 64];   // 32 KB per buffer
  __shared__ __align__(16) u16 Bs[2][256 * 64];   // total 128 KiB
  int t = threadIdx.x;
  int w = t >> 6, l = t & 63;
  // L2-chunked XCD swizzle (see header). bid%8 ~ XCD id on MI355X dispatch.
  int bid = blockIdx.x;
  int xcd = bid & 7, i = bid >> 3;            // i in [0,180)
  int chunk = i / 30, within = i - chunk * 30;
  int cr = within % 5, cc = within / 5;       // col-major in chunk: 5 consecutive
  int by = xcd * 5 + cr, bx = chunk * 6 + cc; //   blocks share one B-panel
  int row0 = by * 256, col0 = bx * 256;
  int wr = w >> 2, wc = w & 3;       // wave grid 2 (M) x 4 (N)
  int lr = l & 15;
  int koff = (l >> 4) * 16;          // byte offset of k-octet inside 128B row
  int swzr = (lr & 7) << 4;          // T2 read-side XOR (row&7 == lr&7: bases %16==0)
  // staging geometry: thread t covers one 16B chunk; row-in-64 rb, chunk t&7
  int rb = t >> 3;                                  // 0..63
  int csw = ((t & 7) ^ (rb & 7)) * 8;               // pre-swizzled source col
  const u16* baseA = A + (size_t)(row0 + rb) * FDIM + csw;
  const u16* baseB = B + (size_t)(col0 + rb) * FDIM + csw;

  f32x4 acc[8][4] = {};
  short8 a[4][2], b0[2][2], b1[2][2];

  auto stA = [&](int buf, int h, int s) {
    const u16* g = baseA + (size_t)(h * 128) * FDIM + s * 64;
    u16* lp = (u16*)&As[buf][0] + h * 8192 + (w << 9);
    GLL16(g, lp);
    GLL16(g + (size_t)64 * FDIM, lp + 4096);
  };
  auto stB = [&](int buf, int h, int s) {
    const u16* g = baseB + (size_t)(h * 128) * FDIM + s * 64;
    u16* lp = (u16*)&Bs[buf][0] + h * 8192 + (w << 9);
    GLL16(g, lp);
    GLL16(g + (size_t)64 * FDIM, lp + 4096);
  };
  auto ldA = [&](int buf, int mo) {
#pragma unroll
    for (int m = 0; m < 4; m++)
#pragma unroll
      for (int c = 0; c < 2; c++) {
        int row = wr * 128 + (mo + m) * 16 + lr;
        int off = row * 128 + ((c * 64 + koff) ^ swzr);
        a[m][c] = *(const short8*)((const char*)&As[buf][0] + off);
      }
  };
  auto ldB = [&](int buf, short8 (*bb)[2], int no) {
#pragma unroll
    for (int n = 0; n < 2; n++)
#pragma unroll
      for (int c = 0; c < 2; c++) {
        int row = wc * 64 + (no + n) * 16 + lr;
        int off = row * 128 + ((c * 64 + koff) ^ swzr);
        bb[n][c] = *(const short8*)((const char*)&Bs[buf][0] + off);
      }
  };
  auto mm8 = [&](short8 (*bb)[2], int mo, int no) {   // 16 MFMA, T5-wrapped
    __builtin_amdgcn_s_setprio(1);
#pragma unroll
    for (int m = 0; m < 4; m++)
#pragma unroll
      for (int n = 0; n < 2; n++)
#pragma unroll
        for (int c = 0; c < 2; c++)
          acc[mo + m][no + n] = __builtin_amdgcn_mfma_f32_16x16x32_bf16(
              a[m][c], bb[n][c], acc[mo + m][no + n], 0, 0, 0);
    __builtin_amdgcn_s_setprio(0);
  };

  // prologue: tile0 all 4 halves (oldest 8 loads), then tile1 {B0, A0}
  stA(0, 0, 0); stA(0, 1, 0); stB(0, 0, 0); stB(0, 1, 0);
  stB(1, 0, 1); stA(1, 0, 1);
  asm volatile("s_waitcnt vmcnt(4)" ::: "memory");   // tile0 landed, 2 halves fly
  __builtin_amdgcn_s_barrier();

#pragma unroll
  for (int s = 0; s < 12; s++) {      // 12 K-tiles of 64
    int P = s & 1;
    // ---- p0: quadrant (m0-3, n0-1)
    ldA(P, 0); ldB(P, b0, 0);
    if (s + 1 < 12) stB(P ^ 1, 1, s + 1);
    __builtin_amdgcn_s_barrier();
    mm8(b0, 0, 0);
    __builtin_amdgcn_s_barrier();
    // ---- p1: quadrant (m0-3, n2-3)
    ldB(P, b1, 2);
    if (s + 1 < 12) stA(P ^ 1, 1, s + 1);
    __builtin_amdgcn_s_barrier();
    mm8(b1, 0, 2);
    __builtin_amdgcn_s_barrier();
    // ---- p2: quadrant (m4-7, n2-3)
    ldA(P, 4);
    if (s + 2 < 12) stB(P, 0, s + 2);
    __builtin_amdgcn_s_barrier();
    mm8(b1, 4, 2);
    __builtin_amdgcn_s_barrier();
    // ---- p3: quadrant (m4-7, n0-1)
    if (s + 2 < 12) stA(P, 0, s + 2);
    __builtin_amdgcn_s_barrier();
    mm8(b0, 4, 0);
    if (s < 11) {
      if (s <= 9) asm volatile("s_waitcnt vmcnt(4)" ::: "memory");
      else        asm volatile("s_waitcnt vmcnt(0)" ::: "memory");
    }
    __builtin_amdgcn_s_barrier();
  }

  // epilogue: C/D layout col=lane&15, row=(lane>>4)*4+reg.
  // NONTEMPORAL stores: C is write-once, read only by the later k_att —
  // keep the 188 MB stream from evicting A/B out of L2/L3.
  int lg = l >> 4;
#pragma unroll
  for (int m = 0; m < 8; m++)
#pragma unroll
    for (int n = 0; n < 4; n++) {
      int col = col0 + wc * 64 + n * 16 + lr;
#pragma unroll
      for (int r = 0; r < 4; r++) {
        int row = row0 + wr * 128 + m * 16 + lg * 4 + r;
        __builtin_nontemporal_store(f32_bf16(acc[m][n][r]),
                                    &C[(size_t)row * KDIM + col]);
      }
    }
}

// ---- fused attention softmax + aggregation + head-mean + bias, ONE WAVE PER NODE.
//      out[n,c] = (1/12) sum_h sum_e alpha[e,h] * Hbig[src_e, h*768+c] + bias[c]  ----
__global__ void k_att(const u16* __restrict__ Hbig, const int* __restrict__ ei,
                      const int* __restrict__ offs, const int* __restrict__ elist,
                      const float* __restrict__ sd, const float* __restrict__ bias,
                      float* __restrict__ out) {
  int t = threadIdx.x, w = t >> 6, l = t & 63;
  int n = blockIdx.x * 4 + w;
  __shared__ int   srcsS[4][DMAX];
  __shared__ float alphS[4][NHEADS * DMAX];
  if (n >= NNODES) return;          // no block barriers below
  int* srcs = srcsS[w];
  float* alph = alphS[w];
  int beg = offs[n];
  int deg = offs[n + 1] - beg;
  if (deg > DMAX) deg = DMAX;
  if (l < deg) {
    int e = elist[beg + l];
    srcs[l] = (e < NEDGES) ? ei[e] : e - NEDGES;
  }
  __builtin_amdgcn_wave_barrier();
  for (int p = l; p < deg * NHEADS; p += 64) {
    int i = p / NHEADS, h = p - i * NHEADS;
    float v = sd[srcs[i] * 24 + h] + sd[n * 24 + 12 + h];
    v = (v > 0.f) ? v : NEG_SLOPE * v;
    alph[h * DMAX + i] = v;
  }
  __builtin_amdgcn_wave_barrier();
  if (l < NHEADS) {
    float m = -1e30f;
    for (int i = 0; i < deg; i++) m = fmaxf(m, alph[l * DMAX + i]);
    float s = 0.f;
    for (int i = 0; i < deg; i++) {
      float ex = expf(alph[l * DMAX + i] - m);
      alph[l * DMAX + i] = ex;
      s += ex;
    }
    float inv = 1.f / (s + 1e-16f);
    for (int i = 0; i < deg; i++) alph[l * DMAX + i] *= inv;
  }
  __builtin_amdgcn_wave_barrier();
  // 3 passes of 256 cols; lane l covers cols [4l, 4l+4)
#pragma unroll
  for (int pass = 0; pass < 3; pass++) {
    float4 acc = make_float4(0.f, 0.f, 0.f, 0.f);
    for (int i = 0; i < deg; i++) {
      const u16* hb = Hbig + (size_t)srcs[i] * KDIM + pass * 256 + 4 * l;
#pragma unroll
      for (int h = 0; h < NHEADS; h++) {
        ushort4 hv = *(const ushort4*)(hb + h * CDIM);
        float a = alph[h * DMAX + i];
        acc.x += a * bf16_f32(hv.x);
        acc.y += a * bf16_f32(hv.y);
        acc.z += a * bf16_f32(hv.z);
        acc.w += a * bf16_f32(hv.w);
      }
    }
    int c = pass * 256 + 4 * l;
    const float sc = 1.f / 12.f;
    float4 ov;
    ov.x = acc.x * sc + bias[c + 0];
    ov.y = acc.y * sc + bias[c + 1];
    ov.z = acc.z * sc + bias[c + 2];
    ov.w = acc.w * sc + bias[c + 3];
    *(float4*)(out + (size_t)n * FDIM + c) = ov;
  }
}

// ---------------- graph mean pool (batch is sorted) ----------------
__global__ void k_pool(const float* __restrict__ h2, const int* __restrict__ batch,
                       float* __restrict__ g) {
  int gi = blockIdx.x;
  int c = blockIdx.y * 256 + threadIdx.x;
  int lo = 0, hi = NNODES;
  while (lo < hi) { int mid = (lo + hi) >> 1; if (batch[mid] < gi) lo = mid + 1; else hi = mid; }
  int start = lo;
  lo = start; hi = NNODES;
  while (lo < hi) { int mid = (lo + hi) >> 1; if (batch[mid] < gi + 1) lo = mid + 1; else hi = mid; }
  int end = lo;
  int cnt = end - start; if (cnt < 1) cnt = 1;
  float inv = 1.f / (float)cnt;
  float s = 0.f;
  for (int n = start; n < end; n++) s += h2[(size_t)n * FDIM + c];
  g[gi * FDIM + c] = s * inv;
}

// ---------------- MLP head ----------------
__global__ void k_mlp(const float* __restrict__ g, const float* __restrict__ w1,
                      const float* __restrict__ b1, const float* __restrict__ w2,
                      const float* __restrict__ b2, float* __restrict__ out) {
  int gi = blockIdx.x;
  int t = threadIdx.x;  // 128
  __shared__ float gs[FDIM];
  __shared__ float zs[128];
  for (int i = t; i < FDIM; i += 128) gs[i] = g[gi * FDIM + i];
  __syncthreads();
  float a = b1[t];
  for (int k = 0; k < FDIM; k++) a += gs[k] * w1[k * 128 + t];
  zs[t] = (a > 0.f) ? a : 0.f;
  __syncthreads();
  if (t < 4) {
    float o = b2[t];
    for (int i = 0; i < 128; i++) o += zs[i] * w2[i * 4 + t];
    out[gi * 4 + t] = o;
  }
}

extern "C" void kernel_launch(void* const* d_in, const int* in_sizes, int n_in,
                              void* d_out, int out_size, void* d_ws, size_t ws_size,
                              hipStream_t stream) {
  const float* x    = (const float*)d_in[0];
  const int*   ei   = (const int*)d_in[1];
  const int*   batch= (const int*)d_in[2];
  const float* W1   = (const float*)d_in[3];
  const float* as1  = (const float*)d_in[4];
  const float* ad1  = (const float*)d_in[5];
  const float* b1   = (const float*)d_in[6];
  const float* W2   = (const float*)d_in[7];
  const float* as2  = (const float*)d_in[8];
  const float* ad2  = (const float*)d_in[9];
  const float* b2   = (const float*)d_in[10];
  const float* mw1  = (const float*)d_in[11];
  const float* mb1  = (const float*)d_in[12];
  const float* mw2  = (const float*)d_in[13];
  const float* mb2  = (const float*)d_in[14];
  float* out = (float*)d_out;
  (void)in_sizes; (void)n_in; (void)out_size; (void)ws_size;

  char* wsb = (char*)d_ws;
  size_t off = 0;
  auto alloc = [&](size_t bytes) -> void* {
    void* p = wsb + off;
    off += (bytes + 255) & ~(size_t)255;
    return p;
  };
  // ws budget 256 MiB: Hbig 188.7 + Bt 14.2 + h1 30.7 + h2 30.7 + small ≈ 253.5 MiB.
  // xbf (15.7 MB) ALIASES h2: xbf is dead after k_gemm; h2 written only by layer-1
  // k_att (after gemm) and read by k_pool. No liveness overlap. xbf pad rows
  // [10000,10240) zeroed once; layer-0 k_att writes h1 only, so pad survives to layer 1.
  u16*  Hbig   = (u16*)alloc((size_t)MPAD * KDIM * 2);     // 188.7 MB
  u16*  Bt     = (u16*)alloc((size_t)KDIM * FDIM * 2);     // 14.2 MB
  float* h1    = (float*)alloc((size_t)NNODES * FDIM * 4); // 30.7 MB
  float* h2    = (float*)alloc((size_t)NNODES * FDIM * 4); // 30.7 MB
  u16*  xbf    = (u16*)h2;                                 // alias (see above)
  float* sd    = (float*)alloc((size_t)NNODES * 24 * 4);
  float* Ut    = (float*)alloc((size_t)FDIM * 24 * 4);
  int*  counts = (int*)alloc((size_t)NNODES * 4);
  int*  offs   = (int*)alloc((size_t)(NNODES + 1) * 4);
  int*  cursor = (int*)alloc((size_t)NNODES * 4);
  int*  elist  = (int*)alloc((size_t)ETOT * 4);
  float* gbuf  = (float*)alloc((size_t)NGRAPH * FDIM * 4);

  // CSR by dst (edges identical for both layers)
  hipMemsetAsync(counts, 0, NNODES * 4, stream);
  // zero xbf pad rows so GEMM's padded A rows are well-defined (outputs unread)
  hipMemsetAsync(xbf + (size_t)NNODES * FDIM, 0, (size_t)(MPAD - NNODES) * FDIM * 2, stream);
  k_count<<<(ETOT + 255) / 256, 256, 0, stream>>>(ei + NEDGES, counts);
  k_scan<<<1, 256, 0, stream>>>(counts, offs);
  k_seed<<<(NNODES + 255) / 256, 256, 0, stream>>>(offs, cursor);
  k_scatter<<<(ETOT + 255) / 256, 256, 0, stream>>>(ei + NEDGES, cursor, elist);

  for (int layer = 0; layer < 2; layer++) {
    const float* xin  = layer ? h1  : x;
    const float* W    = layer ? W2  : W1;
    const float* asrc = layer ? as2 : as1;
    const float* adst = layer ? ad2 : ad1;
    const float* bb   = layer ? b2  : b1;
    float* hout       = layer ? h2  : h1;

    k_U<<<FDIM, 256, 0, stream>>>(W, asrc, adst, Ut);
    k_sd<<<(NNODES + 19) / 20, 256, 0, stream>>>(xin, Ut, sd, xbf);
    k_trans<<<dim3(FDIM / 32, KDIM / 32), dim3(32, 8), 0, stream>>>(W, Bt);
    k_gemm<<<dim3((MPAD / 256) * (KDIM / 256)), 512, 0, stream>>>(xbf, Bt, Hbig);
    k_att<<<(NNODES + 3) / 4, 256, 0, stream>>>(Hbig, ei, offs, elist, sd, bb, hout);
  }

  k_pool<<<dim3(NGRAPH, 3), 256, 0, stream>>>(h2, batch, gbuf);
  k_mlp<<<NGRAPH, 128, 0, stream>>>(gbuf, mw1, mb1, mw2, mb2, out);
}

// Round 6
// 878.210 us; speedup vs baseline: 1.1447x; 1.1447x over previous
//
#include <hip/hip_runtime.h>
#include <stdint.h>

typedef unsigned short u16;
typedef unsigned int   u32;

#define NNODES 10000
#define NEDGES 20000
#define ETOT   30000
#define NHEADS 12
#define CDIM   768
#define FDIM   768
#define KDIM   9216
#define NGRAPH 64
#define MPAD   10240   // 40*256 row tiles for the 256^2 GEMM; pad rows zeroed, never read
#define NEG_SLOPE 0.2f
#define DMAX   32      // max in-degree incl. self-loop; max of 10000 Poisson(2) ~ 14

typedef __attribute__((ext_vector_type(8))) short short8;
typedef __attribute__((ext_vector_type(4))) float f32x4;

__device__ __forceinline__ u16 f32_bf16(float f) {
  u32 u = __float_as_uint(f);
  u = (u + 0x7FFFu + ((u >> 16) & 1u)) >> 16;
  return (u16)u;
}
__device__ __forceinline__ float bf16_f32(u16 v) {
  return __uint_as_float(((u32)v) << 16);
}

// ---------------- CSR build ----------------
__global__ void k_count(const int* __restrict__ dste, int* __restrict__ counts) {
  int e = blockIdx.x * blockDim.x + threadIdx.x;
  if (e >= ETOT) return;
  int dst;
  if (e < NEDGES) dst = dste[e]; else dst = e - NEDGES;
  atomicAdd(&counts[dst], 1);
}

__global__ void k_scan(const int* __restrict__ counts, int* __restrict__ offs) {
  __shared__ int part[256];
  int t = threadIdx.x;
  const int chunk = 40;
  int beg = t * chunk;
  int end = beg + chunk; if (end > NNODES) end = NNODES;
  int s = 0;
  for (int i = beg; i < end && i < NNODES; i++) s += counts[i];
  part[t] = s;
  __syncthreads();
  for (int d = 1; d < 256; d <<= 1) {
    int v = (t >= d) ? part[t - d] : 0;
    __syncthreads();
    part[t] += v;
    __syncthreads();
  }
  int base = (t == 0) ? 0 : part[t - 1];
  for (int i = beg; i < end && i < NNODES; i++) { offs[i] = base; base += counts[i]; }
  if (t == 255) offs[NNODES] = base;
}

__global__ void k_seed(const int* __restrict__ offs, int* __restrict__ cursor) {
  int n = blockIdx.x * blockDim.x + threadIdx.x;
  if (n < NNODES) cursor[n] = offs[n];
}

__global__ void k_scatter(const int* __restrict__ dste, int* __restrict__ cursor,
                          int* __restrict__ elist) {
  int e = blockIdx.x * blockDim.x + threadIdx.x;
  if (e >= ETOT) return;
  int dst;
  if (e < NEDGES) dst = dste[e]; else dst = e - NEDGES;
  int pos = atomicAdd(&cursor[dst], 1);
  elist[pos] = e;
}

// ------- Ut[o*768+k] = sum_c W[k, h*768+c] * a[h, c] ; 4 waves x 6 o's per block -------
__global__ void k_U(const float* __restrict__ W, const float* __restrict__ a_src,
                    const float* __restrict__ a_dst, float* __restrict__ Ut) {
  int k = blockIdx.x;
  int t = threadIdx.x, w = t >> 6, l = t & 63;
  const float* Wrow = W + (size_t)k * KDIM;
#pragma unroll
  for (int q = 0; q < 6; q++) {
    int o = w * 6 + q;
    int h = (o < 12) ? o : o - 12;
    const float* av = (o < 12) ? (a_src + h * CDIM) : (a_dst + h * CDIM);
    const float* wr = Wrow + h * CDIM;
    float p = 0.f;
    for (int c = l; c < CDIM; c += 64) p += wr[c] * av[c];
#pragma unroll
    for (int d = 32; d > 0; d >>= 1) p += __shfl_down(p, d, 64);
    if (l == 0) Ut[o * FDIM + k] = p;
  }
}

// ---- sd: Ut staged in LDS once per block; 20 nodes/block. Also writes xbf (GEMM A). ----
__global__ void k_sd(const float* __restrict__ xin, const float* __restrict__ Ut,
                     float* __restrict__ sd, u16* __restrict__ xbf) {
  __shared__ float UtS[24 * FDIM];   // 73728 B
  int t = threadIdx.x, w = t >> 6, l = t & 63;
  const float4* U4 = (const float4*)Ut;
  float4* S4 = (float4*)UtS;
  for (int i = t; i < 24 * FDIM / 4; i += 256) S4[i] = U4[i];
  __syncthreads();
#pragma unroll
  for (int rep = 0; rep < 5; rep++) {
    int n = blockIdx.x * 20 + w * 5 + rep;
    if (n >= NNODES) continue;
    const float* xr = xin + (size_t)n * FDIM;
    float4 x0 = *(const float4*)(xr + 4 * l);
    float4 x1 = *(const float4*)(xr + 4 * l + 256);
    float4 x2 = *(const float4*)(xr + 4 * l + 512);
    // bf16 copy for the GEMM A operand
    u16* xb = xbf + (size_t)n * FDIM + 4 * l;
    ushort4 p0, p1, p2;
    p0.x = f32_bf16(x0.x); p0.y = f32_bf16(x0.y); p0.z = f32_bf16(x0.z); p0.w = f32_bf16(x0.w);
    p1.x = f32_bf16(x1.x); p1.y = f32_bf16(x1.y); p1.z = f32_bf16(x1.z); p1.w = f32_bf16(x1.w);
    p2.x = f32_bf16(x2.x); p2.y = f32_bf16(x2.y); p2.z = f32_bf16(x2.z); p2.w = f32_bf16(x2.w);
    *(ushort4*)xb = p0;
    *(ushort4*)(xb + 256) = p1;
    *(ushort4*)(xb + 512) = p2;
#pragma unroll
    for (int o = 0; o < 24; o++) {
      const float4* up = (const float4*)(UtS + o * FDIM + 4 * l);
      float4 u0 = up[0];
      float4 u1 = up[64];
      float4 u2 = up[128];
      float a = x0.x * u0.x + x0.y * u0.y + x0.z * u0.z + x0.w * u0.w
              + x1.x * u1.x + x1.y * u1.y + x1.z * u1.z + x1.w * u1.w
              + x2.x * u2.x + x2.y * u2.y + x2.z * u2.z + x2.w * u2.w;
#pragma unroll
      for (int d = 32; d > 0; d >>= 1) a += __shfl_xor(a, d, 64);
      if (l == 0) sd[n * 24 + o] = a;
    }
  }
}

// -------- Bt[j, k] = bf16(W[k, j])  — straight transpose, row length 768 --------
__global__ void k_trans(const float* __restrict__ W, u16* __restrict__ Bt) {
  int kt = blockIdx.x * 32, jt = blockIdx.y * 32;
  int tx = threadIdx.x, ty = threadIdx.y;  // 32, 8
  __shared__ float tile[32][33];
#pragma unroll
  for (int r = 0; r < 4; r++)
    tile[ty + 8 * r][tx] = W[(size_t)(kt + ty + 8 * r) * KDIM + jt + tx];
  __syncthreads();
#pragma unroll
  for (int r = 0; r < 4; r++)
    Bt[(size_t)(jt + ty + 8 * r) * FDIM + kt + tx] = f32_bf16(tile[tx][ty + 8 * r]);
}

// ============================================================================
// GEMM: Hbig[MPAD,9216] bf16 = xbf[MPAD,768] @ Bt[9216,768]^T.
// 256x256 tile, BK=64, 512 threads (2x4 waves, 128x64/wave), 8-phase schedule
// (T2 swizzle / T3+T4 counted vmcnt / T5 setprio — r3: conflicts measured 0).
//
// r5 POST-MORTEM (A/B ledger):
//  - L2-CHUNKED XCD SWIZZLE: CONFIRMED. FETCH_SIZE 292 -> 93 MB (3.1x).
//    KEEP: XCD x owns rows [5x,5x+5); 5-row x 6-col chunks, col-major
//    inside; per-XCD working set ~4.3 MB ~ L2; bijective (40=8*5, 36=6*6).
//  - NONTEMPORAL C stores: REVERTED. WRITE_SIZE 184 -> 392 MB (2.1x
//    amplification): nt bypasses L2 line assembly, so the wave's scattered
//    32B row-chunks hit HBM as partial-line writes at ~2x bytes and lower
//    achieved write BW (2.64 -> 2.06 TB/s). Plain cached stores let L2
//    assemble full lines (WRITE == C size exactly, r3).
//
// vmcnt ledger (audited r1, unchanged): after prologue 4 in flight; each
// tile issues 8 (p0:(s+1)B1, p1:(s+1)A1, p2:(s+2)B0, p3:(s+2)A0), retires 8
// at tile-end vmcnt(4) => tile s+1 fully landed before its first ds_read;
// following s_barrier extends cross-wave. Tail: s=10 vmcnt(0), s=11 none.
// ============================================================================
#define GLL16(G, L) __builtin_amdgcn_global_load_lds( \
  (const __attribute__((address_space(1))) void*)(G), \
  (__attribute__((address_space(3))) void*)(L), 16, 0, 0)

__global__ __launch_bounds__(512, 2) void k_gemm(const u16* __restrict__ A,
    const u16* __restrict__ B, u16* __restrict__ C) {
  __shared__ __align__(16) u16 As[2][256 * 64];   // 32 KB per buffer
  __shared__ __align__(16) u16 Bs[2][256 * 64];   // total 128 KiB
  int t = threadIdx.x;
  int w = t >> 6, l = t & 63;
  // L2-chunked XCD swizzle (see header). bid%8 ~ XCD id on MI355X dispatch.
  int bid = blockIdx.x;
  int xcd = bid & 7, i = bid >> 3;            // i in [0,180)
  int chunk = i / 30, within = i - chunk * 30;
  int cr = within % 5, cc = within / 5;       // col-major in chunk: 5 consecutive
  int by = xcd * 5 + cr, bx = chunk * 6 + cc; //   blocks share one B-panel
  int row0 = by * 256, col0 = bx * 256;
  int wr = w >> 2, wc = w & 3;       // wave grid 2 (M) x 4 (N)
  int lr = l & 15;
  int koff = (l >> 4) * 16;          // byte offset of k-octet inside 128B row
  int swzr = (lr & 7) << 4;          // T2 read-side XOR (row&7 == lr&7: bases %16==0)
  // staging geometry: thread t covers one 16B chunk; row-in-64 rb, chunk t&7
  int rb = t >> 3;                                  // 0..63
  int csw = ((t & 7) ^ (rb & 7)) * 8;               // pre-swizzled source col
  const u16* baseA = A + (size_t)(row0 + rb) * FDIM + csw;
  const u16* baseB = B + (size_t)(col0 + rb) * FDIM + csw;

  f32x4 acc[8][4] = {};
  short8 a[4][2], b0[2][2], b1[2][2];

  auto stA = [&](int buf, int h, int s) {
    const u16* g = baseA + (size_t)(h * 128) * FDIM + s * 64;
    u16* lp = (u16*)&As[buf][0] + h * 8192 + (w << 9);
    GLL16(g, lp);
    GLL16(g + (size_t)64 * FDIM, lp + 4096);
  };
  auto stB = [&](int buf, int h, int s) {
    const u16* g = baseB + (size_t)(h * 128) * FDIM + s * 64;
    u16* lp = (u16*)&Bs[buf][0] + h * 8192 + (w << 9);
    GLL16(g, lp);
    GLL16(g + (size_t)64 * FDIM, lp + 4096);
  };
  auto ldA = [&](int buf, int mo) {
#pragma unroll
    for (int m = 0; m < 4; m++)
#pragma unroll
      for (int c = 0; c < 2; c++) {
        int row = wr * 128 + (mo + m) * 16 + lr;
        int off = row * 128 + ((c * 64 + koff) ^ swzr);
        a[m][c] = *(const short8*)((const char*)&As[buf][0] + off);
      }
  };
  auto ldB = [&](int buf, short8 (*bb)[2], int no) {
#pragma unroll
    for (int n = 0; n < 2; n++)
#pragma unroll
      for (int c = 0; c < 2; c++) {
        int row = wc * 64 + (no + n) * 16 + lr;
        int off = row * 128 + ((c * 64 + koff) ^ swzr);
        bb[n][c] = *(const short8*)((const char*)&Bs[buf][0] + off);
      }
  };
  auto mm8 = [&](short8 (*bb)[2], int mo, int no) {   // 16 MFMA, T5-wrapped
    __builtin_amdgcn_s_setprio(1);
#pragma unroll
    for (int m = 0; m < 4; m++)
#pragma unroll
      for (int n = 0; n < 2; n++)
#pragma unroll
        for (int c = 0; c < 2; c++)
          acc[mo + m][no + n] = __builtin_amdgcn_mfma_f32_16x16x32_bf16(
              a[m][c], bb[n][c], acc[mo + m][no + n], 0, 0, 0);
    __builtin_amdgcn_s_setprio(0);
  };

  // prologue: tile0 all 4 halves (oldest 8 loads), then tile1 {B0, A0}
  stA(0, 0, 0); stA(0, 1, 0); stB(0, 0, 0); stB(0, 1, 0);
  stB(1, 0, 1); stA(1, 0, 1);
  asm volatile("s_waitcnt vmcnt(4)" ::: "memory");   // tile0 landed, 2 halves fly
  __builtin_amdgcn_s_barrier();

#pragma unroll
  for (int s = 0; s < 12; s++) {      // 12 K-tiles of 64
    int P = s & 1;
    // ---- p0: quadrant (m0-3, n0-1)
    ldA(P, 0); ldB(P, b0, 0);
    if (s + 1 < 12) stB(P ^ 1, 1, s + 1);
    __builtin_amdgcn_s_barrier();
    mm8(b0, 0, 0);
    __builtin_amdgcn_s_barrier();
    // ---- p1: quadrant (m0-3, n2-3)
    ldB(P, b1, 2);
    if (s + 1 < 12) stA(P ^ 1, 1, s + 1);
    __builtin_amdgcn_s_barrier();
    mm8(b1, 0, 2);
    __builtin_amdgcn_s_barrier();
    // ---- p2: quadrant (m4-7, n2-3)
    ldA(P, 4);
    if (s + 2 < 12) stB(P, 0, s + 2);
    __builtin_amdgcn_s_barrier();
    mm8(b1, 4, 2);
    __builtin_amdgcn_s_barrier();
    // ---- p3: quadrant (m4-7, n0-1)
    if (s + 2 < 12) stA(P, 0, s + 2);
    __builtin_amdgcn_s_barrier();
    mm8(b0, 4, 0);
    if (s < 11) {
      if (s <= 9) asm volatile("s_waitcnt vmcnt(4)" ::: "memory");
      else        asm volatile("s_waitcnt vmcnt(0)" ::: "memory");
    }
    __builtin_amdgcn_s_barrier();
  }

  // epilogue: C/D layout col=lane&15, row=(lane>>4)*4+reg.
  // PLAIN cached stores (r5 lesson): L2 assembles the wave's scattered 32B
  // row-chunks into full lines -> WRITE_SIZE == C size exactly.
  int lg = l >> 4;
#pragma unroll
  for (int m = 0; m < 8; m++)
#pragma unroll
    for (int n = 0; n < 4; n++) {
      int col = col0 + wc * 64 + n * 16 + lr;
#pragma unroll
      for (int r = 0; r < 4; r++) {
        int row = row0 + wr * 128 + m * 16 + lg * 4 + r;
        C[(size_t)row * KDIM + col] = f32_bf16(acc[m][n][r]);
      }
    }
}

// ---- fused attention softmax + aggregation + head-mean + bias, ONE WAVE PER NODE.
//      out[n,c] = (1/12) sum_h sum_e alpha[e,h] * Hbig[src_e, h*768+c] + bias[c]  ----
__global__ void k_att(const u16* __restrict__ Hbig, const int* __restrict__ ei,
                      const int* __restrict__ offs, const int* __restrict__ elist,
                      const float* __restrict__ sd, const float* __restrict__ bias,
                      float* __restrict__ out) {
  int t = threadIdx.x, w = t >> 6, l = t & 63;
  int n = blockIdx.x * 4 + w;
  __shared__ int   srcsS[4][DMAX];
  __shared__ float alphS[4][NHEADS * DMAX];
  if (n >= NNODES) return;          // no block barriers below
  int* srcs = srcsS[w];
  float* alph = alphS[w];
  int beg = offs[n];
  int deg = offs[n + 1] - beg;
  if (deg > DMAX) deg = DMAX;
  if (l < deg) {
    int e = elist[beg + l];
    srcs[l] = (e < NEDGES) ? ei[e] : e - NEDGES;
  }
  __builtin_amdgcn_wave_barrier();
  for (int p = l; p < deg * NHEADS; p += 64) {
    int i = p / NHEADS, h = p - i * NHEADS;
    float v = sd[srcs[i] * 24 + h] + sd[n * 24 + 12 + h];
    v = (v > 0.f) ? v : NEG_SLOPE * v;
    alph[h * DMAX + i] = v;
  }
  __builtin_amdgcn_wave_barrier();
  if (l < NHEADS) {
    float m = -1e30f;
    for (int i = 0; i < deg; i++) m = fmaxf(m, alph[l * DMAX + i]);
    float s = 0.f;
    for (int i = 0; i < deg; i++) {
      float ex = expf(alph[l * DMAX + i] - m);
      alph[l * DMAX + i] = ex;
      s += ex;
    }
    float inv = 1.f / (s + 1e-16f);
    for (int i = 0; i < deg; i++) alph[l * DMAX + i] *= inv;
  }
  __builtin_amdgcn_wave_barrier();
  // 3 passes of 256 cols; lane l covers cols [4l, 4l+4)
#pragma unroll
  for (int pass = 0; pass < 3; pass++) {
    float4 acc = make_float4(0.f, 0.f, 0.f, 0.f);
    for (int i = 0; i < deg; i++) {
      const u16* hb = Hbig + (size_t)srcs[i] * KDIM + pass * 256 + 4 * l;
#pragma unroll
      for (int h = 0; h < NHEADS; h++) {
        ushort4 hv = *(const ushort4*)(hb + h * CDIM);
        float a = alph[h * DMAX + i];
        acc.x += a * bf16_f32(hv.x);
        acc.y += a * bf16_f32(hv.y);
        acc.z += a * bf16_f32(hv.z);
        acc.w += a * bf16_f32(hv.w);
      }
    }
    int c = pass * 256 + 4 * l;
    const float sc = 1.f / 12.f;
    float4 ov;
    ov.x = acc.x * sc + bias[c + 0];
    ov.y = acc.y * sc + bias[c + 1];
    ov.z = acc.z * sc + bias[c + 2];
    ov.w = acc.w * sc + bias[c + 3];
    *(float4*)(out + (size_t)n * FDIM + c) = ov;
  }
}

// ---------------- graph mean pool (batch is sorted) ----------------
__global__ void k_pool(const float* __restrict__ h2, const int* __restrict__ batch,
                       float* __restrict__ g) {
  int gi = blockIdx.x;
  int c = blockIdx.y * 256 + threadIdx.x;
  int lo = 0, hi = NNODES;
  while (lo < hi) { int mid = (lo + hi) >> 1; if (batch[mid] < gi) lo = mid + 1; else hi = mid; }
  int start = lo;
  lo = start; hi = NNODES;
  while (lo < hi) { int mid = (lo + hi) >> 1; if (batch[mid] < gi + 1) lo = mid + 1; else hi = mid; }
  int end = lo;
  int cnt = end - start; if (cnt < 1) cnt = 1;
  float inv = 1.f / (float)cnt;
  float s = 0.f;
  for (int n = start; n < end; n++) s += h2[(size_t)n * FDIM + c];
  g[gi * FDIM + c] = s * inv;
}

// ---------------- MLP head ----------------
__global__ void k_mlp(const float* __restrict__ g, const float* __restrict__ w1,
                      const float* __restrict__ b1, const float* __restrict__ w2,
                      const float* __restrict__ b2, float* __restrict__ out) {
  int gi = blockIdx.x;
  int t = threadIdx.x;  // 128
  __shared__ float gs[FDIM];
  __shared__ float zs[128];
  for (int i = t; i < FDIM; i += 128) gs[i] = g[gi * FDIM + i];
  __syncthreads();
  float a = b1[t];
  for (int k = 0; k < FDIM; k++) a += gs[k] * w1[k * 128 + t];
  zs[t] = (a > 0.f) ? a : 0.f;
  __syncthreads();
  if (t < 4) {
    float o = b2[t];
    for (int i = 0; i < 128; i++) o += zs[i] * w2[i * 4 + t];
    out[gi * 4 + t] = o;
  }
}

extern "C" void kernel_launch(void* const* d_in, const int* in_sizes, int n_in,
                              void* d_out, int out_size, void* d_ws, size_t ws_size,
                              hipStream_t stream) {
  const float* x    = (const float*)d_in[0];
  const int*   ei   = (const int*)d_in[1];
  const int*   batch= (const int*)d_in[2];
  const float* W1   = (const float*)d_in[3];
  const float* as1  = (const float*)d_in[4];
  const float* ad1  = (const float*)d_in[5];
  const float* b1   = (const float*)d_in[6];
  const float* W2   = (const float*)d_in[7];
  const float* as2  = (const float*)d_in[8];
  const float* ad2  = (const float*)d_in[9];
  const float* b2   = (const float*)d_in[10];
  const float* mw1  = (const float*)d_in[11];
  const float* mb1  = (const float*)d_in[12];
  const float* mw2  = (const float*)d_in[13];
  const float* mb2  = (const float*)d_in[14];
  float* out = (float*)d_out;
  (void)in_sizes; (void)n_in; (void)out_size; (void)ws_size;

  char* wsb = (char*)d_ws;
  size_t off = 0;
  auto alloc = [&](size_t bytes) -> void* {
    void* p = wsb + off;
    off += (bytes + 255) & ~(size_t)255;
    return p;
  };
  // ws budget 256 MiB: Hbig 188.7 + Bt 14.2 + h1 30.7 + h2 30.7 + small ≈ 253.5 MiB.
  // xbf (15.7 MB) ALIASES h2: xbf is dead after k_gemm; h2 written only by layer-1
  // k_att (after gemm) and read by k_pool. No liveness overlap. xbf pad rows
  // [10000,10240) zeroed once; layer-0 k_att writes h1 only, so pad survives to layer 1.
  u16*  Hbig   = (u16*)alloc((size_t)MPAD * KDIM * 2);     // 188.7 MB
  u16*  Bt     = (u16*)alloc((size_t)KDIM * FDIM * 2);     // 14.2 MB
  float* h1    = (float*)alloc((size_t)NNODES * FDIM * 4); // 30.7 MB
  float* h2    = (float*)alloc((size_t)NNODES * FDIM * 4); // 30.7 MB
  u16*  xbf    = (u16*)h2;                                 // alias (see above)
  float* sd    = (float*)alloc((size_t)NNODES * 24 * 4);
  float* Ut    = (float*)alloc((size_t)FDIM * 24 * 4);
  int*  counts = (int*)alloc((size_t)NNODES * 4);
  int*  offs   = (int*)alloc((size_t)(NNODES + 1) * 4);
  int*  cursor = (int*)alloc((size_t)NNODES * 4);
  int*  elist  = (int*)alloc((size_t)ETOT * 4);
  float* gbuf  = (float*)alloc((size_t)NGRAPH * FDIM * 4);

  // CSR by dst (edges identical for both layers)
  hipMemsetAsync(counts, 0, NNODES * 4, stream);
  // zero xbf pad rows so GEMM's padded A rows are well-defined (outputs unread)
  hipMemsetAsync(xbf + (size_t)NNODES * FDIM, 0, (size_t)(MPAD - NNODES) * FDIM * 2, stream);
  k_count<<<(ETOT + 255) / 256, 256, 0, stream>>>(ei + NEDGES, counts);
  k_scan<<<1, 256, 0, stream>>>(counts, offs);
  k_seed<<<(NNODES + 255) / 256, 256, 0, stream>>>(offs, cursor);
  k_scatter<<<(ETOT + 255) / 256, 256, 0, stream>>>(ei + NEDGES, cursor, elist);

  for (int layer = 0; layer < 2; layer++) {
    const float* xin  = layer ? h1  : x;
    const float* W    = layer ? W2  : W1;
    const float* asrc = layer ? as2 : as1;
    const float* adst = layer ? ad2 : ad1;
    const float* bb   = layer ? b2  : b1;
    float* hout       = layer ? h2  : h1;

    k_U<<<FDIM, 256, 0, stream>>>(W, asrc, adst, Ut);
    k_sd<<<(NNODES + 19) / 20, 256, 0, stream>>>(xin, Ut, sd, xbf);
    k_trans<<<dim3(FDIM / 32, KDIM / 32), dim3(32, 8), 0, stream>>>(W, Bt);
    k_gemm<<<dim3((MPAD / 256) * (KDIM / 256)), 512, 0, stream>>>(xbf, Bt, Hbig);
    k_att<<<(NNODES + 3) / 4, 256, 0, stream>>>(Hbig, ei, offs, elist, sd, bb, hout);
  }

  k_pool<<<dim3(NGRAPH, 3), 256, 0, stream>>>(h2, batch, gbuf);
  k_mlp<<<NGRAPH, 128, 0, stream>>>(gbuf, mw1, mb1, mw2, mb2, out);
}

// Round 7
// 876.853 us; speedup vs baseline: 1.1465x; 1.0015x over previous
//
#include <hip/hip_runtime.h>
#include <stdint.h>

typedef unsigned short u16;
typedef unsigned int   u32;

#define NNODES 10000
#define NEDGES 20000
#define ETOT   30000
#define NHEADS 12
#define CDIM   768
#define FDIM   768
#define KDIM   9216    // h*768+k flattened head-input dim (GEMM K); also y row width
#define NGRAPH 64
#define MPAD   10240   // y padded rows: 80*128 row tiles; pad rows zeroed, outputs guarded
#define NEG_SLOPE 0.2f
#define DMAX   32      // max in-degree incl. self-loop; max of 10000 Poisson(2) ~ 14

typedef __attribute__((ext_vector_type(8))) short short8;
typedef __attribute__((ext_vector_type(4))) float f32x4;

__device__ __forceinline__ u16 f32_bf16(float f) {
  u32 u = __float_as_uint(f);
  u = (u + 0x7FFFu + ((u >> 16) & 1u)) >> 16;
  return (u16)u;
}
__device__ __forceinline__ float bf16_f32(u16 v) {
  return __uint_as_float(((u32)v) << 16);
}

// ---------------- CSR build ----------------
__global__ void k_count(const int* __restrict__ dste, int* __restrict__ counts) {
  int e = blockIdx.x * blockDim.x + threadIdx.x;
  if (e >= ETOT) return;
  int dst;
  if (e < NEDGES) dst = dste[e]; else dst = e - NEDGES;
  atomicAdd(&counts[dst], 1);
}

__global__ void k_scan(const int* __restrict__ counts, int* __restrict__ offs) {
  __shared__ int part[256];
  int t = threadIdx.x;
  const int chunk = 40;
  int beg = t * chunk;
  int end = beg + chunk; if (end > NNODES) end = NNODES;
  int s = 0;
  for (int i = beg; i < end && i < NNODES; i++) s += counts[i];
  part[t] = s;
  __syncthreads();
  for (int d = 1; d < 256; d <<= 1) {
    int v = (t >= d) ? part[t - d] : 0;
    __syncthreads();
    part[t] += v;
    __syncthreads();
  }
  int base = (t == 0) ? 0 : part[t - 1];
  for (int i = beg; i < end && i < NNODES; i++) { offs[i] = base; base += counts[i]; }
  if (t == 255) offs[NNODES] = base;
}

__global__ void k_seed(const int* __restrict__ offs, int* __restrict__ cursor) {
  int n = blockIdx.x * blockDim.x + threadIdx.x;
  if (n < NNODES) cursor[n] = offs[n];
}

__global__ void k_scatter(const int* __restrict__ dste, int* __restrict__ cursor,
                          int* __restrict__ elist) {
  int e = blockIdx.x * blockDim.x + threadIdx.x;
  if (e >= ETOT) return;
  int dst;
  if (e < NEDGES) dst = dste[e]; else dst = e - NEDGES;
  int pos = atomicAdd(&cursor[dst], 1);
  elist[pos] = e;
}

// ------- Ut[o*768+k] = sum_c W[k, h*768+c] * a[h, c] ; 4 waves x 6 o's per block -------
__global__ void k_U(const float* __restrict__ W, const float* __restrict__ a_src,
                    const float* __restrict__ a_dst, float* __restrict__ Ut) {
  int k = blockIdx.x;
  int t = threadIdx.x, w = t >> 6, l = t & 63;
  const float* Wrow = W + (size_t)k * KDIM;
#pragma unroll
  for (int q = 0; q < 6; q++) {
    int o = w * 6 + q;
    int h = (o < 12) ? o : o - 12;
    const float* av = (o < 12) ? (a_src + h * CDIM) : (a_dst + h * CDIM);
    const float* wr = Wrow + h * CDIM;
    float p = 0.f;
    for (int c = l; c < CDIM; c += 64) p += wr[c] * av[c];
#pragma unroll
    for (int d = 32; d > 0; d >>= 1) p += __shfl_down(p, d, 64);
    if (l == 0) Ut[o * FDIM + k] = p;
  }
}

// ---- sd: Ut staged in LDS once per block; 20 nodes/block. (xbf write removed:
//      the aggregate-then-transform restructure no longer needs bf16 x.) ----
__global__ void k_sd(const float* __restrict__ xin, const float* __restrict__ Ut,
                     float* __restrict__ sd) {
  __shared__ float UtS[24 * FDIM];   // 73728 B
  int t = threadIdx.x, w = t >> 6, l = t & 63;
  const float4* U4 = (const float4*)Ut;
  float4* S4 = (float4*)UtS;
  for (int i = t; i < 24 * FDIM / 4; i += 256) S4[i] = U4[i];
  __syncthreads();
#pragma unroll
  for (int rep = 0; rep < 5; rep++) {
    int n = blockIdx.x * 20 + w * 5 + rep;
    if (n >= NNODES) continue;
    const float* xr = xin + (size_t)n * FDIM;
    float4 x0 = *(const float4*)(xr + 4 * l);
    float4 x1 = *(const float4*)(xr + 4 * l + 256);
    float4 x2 = *(const float4*)(xr + 4 * l + 512);
#pragma unroll
    for (int o = 0; o < 24; o++) {
      const float4* up = (const float4*)(UtS + o * FDIM + 4 * l);
      float4 u0 = up[0];
      float4 u1 = up[64];
      float4 u2 = up[128];
      float a = x0.x * u0.x + x0.y * u0.y + x0.z * u0.z + x0.w * u0.w
              + x1.x * u1.x + x1.y * u1.y + x1.z * u1.z + x1.w * u1.w
              + x2.x * u2.x + x2.y * u2.y + x2.z * u2.z + x2.w * u2.w;
#pragma unroll
      for (int d = 32; d > 0; d >>= 1) a += __shfl_xor(a, d, 64);
      if (l == 0) sd[n * 24 + o] = a;
    }
  }
}

// -------- Bt2[c, h*768+k] = bf16(W[k, h*768+c]) — per-head transpose.
//          GEMM B-operand for out = (1/12) sum_h y_h @ W_h. --------
__global__ void k_trans2(const float* __restrict__ W, u16* __restrict__ Bt2) {
  int kt = blockIdx.x * 32, jt = blockIdx.y * 32;   // j = h*768+c; 768%32==0 -> one head/tile
  int tx = threadIdx.x, ty = threadIdx.y;  // 32, 8
  __shared__ float tile[32][33];
  int h0 = jt / 768, c0 = jt - h0 * 768;
#pragma unroll
  for (int r = 0; r < 4; r++)
    tile[ty + 8 * r][tx] = W[(size_t)(kt + ty + 8 * r) * KDIM + jt + tx];
  __syncthreads();
#pragma unroll
  for (int r = 0; r < 4; r++)
    Bt2[(size_t)(c0 + ty + 8 * r) * KDIM + h0 * 768 + kt + tx] = f32_bf16(tile[tx][ty + 8 * r]);
}

// ---- k_agg: softmax + aggregation IN INPUT SPACE (replaces k_att's Hbig gather).
//      y[n, h*768+k] = sum_e alpha[e,h] * xin[src_e, k]   (f32 acc, bf16 store)
//      One wave per node; gathers 3KB rows from the L3-resident xin (30 MB)
//      instead of 18KB rows from the 188 MB Hbig — 6x less gather traffic. ----
__global__ void k_agg(const float* __restrict__ xin, const int* __restrict__ ei,
                      const int* __restrict__ offs, const int* __restrict__ elist,
                      const float* __restrict__ sd, u16* __restrict__ y) {
  int t = threadIdx.x, w = t >> 6, l = t & 63;
  int n = blockIdx.x * 4 + w;
  __shared__ int   srcsS[4][DMAX];
  __shared__ float alphS[4][NHEADS * DMAX];
  if (n >= NNODES) return;          // no block barriers below
  int* srcs = srcsS[w];
  float* alph = alphS[w];
  int beg = offs[n];
  int deg = offs[n + 1] - beg;
  if (deg > DMAX) deg = DMAX;
  if (l < deg) {
    int e = elist[beg + l];
    srcs[l] = (e < NEDGES) ? ei[e] : e - NEDGES;
  }
  __builtin_amdgcn_wave_barrier();
  for (int p = l; p < deg * NHEADS; p += 64) {
    int i = p / NHEADS, h = p - i * NHEADS;
    float v = sd[srcs[i] * 24 + h] + sd[n * 24 + 12 + h];
    v = (v > 0.f) ? v : NEG_SLOPE * v;
    alph[h * DMAX + i] = v;
  }
  __builtin_amdgcn_wave_barrier();
  if (l < NHEADS) {
    float m = -1e30f;
    for (int i = 0; i < deg; i++) m = fmaxf(m, alph[l * DMAX + i]);
    float s = 0.f;
    for (int i = 0; i < deg; i++) {
      float ex = expf(alph[l * DMAX + i] - m);
      alph[l * DMAX + i] = ex;
      s += ex;
    }
    float inv = 1.f / (s + 1e-16f);
    for (int i = 0; i < deg; i++) alph[l * DMAX + i] *= inv;
  }
  __builtin_amdgcn_wave_barrier();
  // 3 passes of 256 cols; lane l covers cols [4l, 4l+4). acc12 = 48 VGPR (static idx).
#pragma unroll
  for (int pass = 0; pass < 3; pass++) {
    float4 acc12[NHEADS];
#pragma unroll
    for (int h = 0; h < NHEADS; h++) acc12[h] = make_float4(0.f, 0.f, 0.f, 0.f);
    for (int i = 0; i < deg; i++) {
      float4 xs = *(const float4*)(xin + (size_t)srcs[i] * FDIM + pass * 256 + 4 * l);
#pragma unroll
      for (int h = 0; h < NHEADS; h++) {
        float a = alph[h * DMAX + i];
        acc12[h].x += a * xs.x;
        acc12[h].y += a * xs.y;
        acc12[h].z += a * xs.z;
        acc12[h].w += a * xs.w;
      }
    }
    u16* yr = y + (size_t)n * KDIM + pass * 256 + 4 * l;
#pragma unroll
    for (int h = 0; h < NHEADS; h++) {
      ushort4 pv;
      pv.x = f32_bf16(acc12[h].x);
      pv.y = f32_bf16(acc12[h].y);
      pv.z = f32_bf16(acc12[h].z);
      pv.w = f32_bf16(acc12[h].w);
      *(ushort4*)(yr + h * CDIM) = pv;
    }
  }
}

// ============================================================================
// GEMM2: hout[n,c] = (1/12) * sum_kk y[n,kk] * Bt2[c,kk] + bias[c]
//        M=10240 (pad), N=768, K=9216. BM=128, BN=256, BK=64 -> 80x3 = 240
//        blocks: SINGLE ROUND on 256 CUs (r6 lesson: the 6 serialized rounds
//        each paid a synchronized fill burst at 1 block/CU). K = 144 tiles ->
//        fill/drain amortized 12x better than the old short-K GEMM; this is
//        the long-K regime where the 8-phase counted-vmcnt schedule is proven.
// 512 thr, waves 2Mx4N, wave tile 64x64 (acc 4x4 f32x4 = 64 VGPR).
// 4 quadrant phases/tile: (m01,n01)(m01,n23)(m23,n23)(m23,n01), 8 MFMA each;
// b_lo/a_lo held in regs across phases so LDS regions free early:
//   A-half0 (rows 0-63) read p0+p2 -> (s+2)A0 issued @p3
//   B-half0 (rows 0-127) read p0+p1 -> (s+2)B0 issued @p2
//   (s+1)B1 @p0, (s+1)A1 @p1 (buf^1, free).
// Issues/tile = 6 (B halves 2 loads, A halves 1). vmcnt ledger: at tile end
// outstanding = 3 newest {(s+2)B0 x2,(s+2)A0} -> vmcnt(3) forces tile s+1
// landed; barrier extends cross-wave. Prologue 9 issues, vmcnt(3). Tail:
// s=142 issues only (143)B1/A1 then vmcnt(0); s=143 compute-only.
// T2 swizzle identical to r6 (rows 128B, XOR (row&7)<<4, pre-swizzled src).
// XCD chunking: xcd gets 10 row-panels x 3 col-blocks (A-panel L2 reuse).
// ============================================================================
#define GLL16(G, L) __builtin_amdgcn_global_load_lds( \
  (const __attribute__((address_space(1))) void*)(G), \
  (__attribute__((address_space(3))) void*)(L), 16, 0, 0)

__global__ __launch_bounds__(512, 2) void k_gemm2(const u16* __restrict__ A,
    const u16* __restrict__ B, float* __restrict__ C, const float* __restrict__ bias) {
  __shared__ __align__(16) u16 As[2][128 * 64];   // 16 KB per buffer
  __shared__ __align__(16) u16 Bs[2][256 * 64];   // 32 KB per buffer; total 96 KiB
  int t = threadIdx.x;
  int w = t >> 6, l = t & 63;
  int bid = blockIdx.x;                       // 240 blocks
  int xcd = bid & 7, j = bid >> 3;            // j in [0,30)
  int by = xcd * 10 + j / 3, bx = j % 3;      // 3 col-blocks consecutive: A-panel L2 reuse
  int row0 = by * 128, col0 = bx * 256;
  int wr = w >> 2, wc = w & 3;       // wave grid 2 (M) x 4 (N)
  int lr = l & 15;
  int koff = (l >> 4) * 16;          // byte offset of k-octet inside 128B row
  int swzr = (lr & 7) << 4;          // T2 read-side XOR (row&7 == lr&7: bases %16==0)
  // staging geometry: thread t covers one 16B chunk; 64 rows per issue
  int rb = t >> 3;                                  // 0..63
  int csw = ((t & 7) ^ (rb & 7)) * 8;               // pre-swizzled source col (u16 units)
  const u16* baseA = A + (size_t)(row0 + rb) * KDIM + csw;
  const u16* baseB = B + (size_t)(col0 + rb) * KDIM + csw;

  f32x4 acc[4][4] = {};
  short8 alo[2][2], ahi[2][2], blo[2][2], bhi[2][2];

  auto stA2 = [&](int buf, int h, int s) {   // A half h: 64 rows, 8 KB, 1 issue
    const u16* g = baseA + (size_t)(h * 64) * KDIM + s * 64;
    GLL16(g, (u16*)&As[buf][0] + h * 4096 + t * 8);
  };
  auto stB2 = [&](int buf, int h, int s) {   // B half h: 128 rows, 16 KB, 2 issues
    const u16* g = baseB + (size_t)(h * 128) * KDIM + s * 64;
    u16* lp = (u16*)&Bs[buf][0] + h * 8192;
    GLL16(g, lp + t * 8);
    GLL16(g + (size_t)64 * KDIM, lp + 4096 + t * 8);
  };
  auto ldA2 = [&](int buf, short8 (*dst)[2], int mo) {
#pragma unroll
    for (int m = 0; m < 2; m++)
#pragma unroll
      for (int c = 0; c < 2; c++) {
        int row = wr * 64 + (mo + m) * 16 + lr;
        int off = row * 128 + ((c * 64 + koff) ^ swzr);
        dst[m][c] = *(const short8*)((const char*)&As[buf][0] + off);
      }
  };
  auto ldB2 = [&](int buf, short8 (*dst)[2], int no) {
#pragma unroll
    for (int n = 0; n < 2; n++)
#pragma unroll
      for (int c = 0; c < 2; c++) {
        int row = wc * 64 + (no + n) * 16 + lr;
        int off = row * 128 + ((c * 64 + koff) ^ swzr);
        dst[n][c] = *(const short8*)((const char*)&Bs[buf][0] + off);
      }
  };
  auto mm8 = [&](short8 (*aa)[2], short8 (*bb)[2], int mo, int no) {   // T5-wrapped
    __builtin_amdgcn_s_setprio(1);
#pragma unroll
    for (int m = 0; m < 2; m++)
#pragma unroll
      for (int n = 0; n < 2; n++)
#pragma unroll
        for (int c = 0; c < 2; c++)
          acc[mo + m][no + n] = __builtin_amdgcn_mfma_f32_16x16x32_bf16(
              aa[m][c], bb[n][c], acc[mo + m][no + n], 0, 0, 0);
    __builtin_amdgcn_s_setprio(0);
  };

#define BAR() __builtin_amdgcn_s_barrier()
#define TILE_STEADY(S, P) do { \
    ldA2(P, alo, 0); ldB2(P, blo, 0); stB2((P) ^ 1, 1, (S) + 1); \
    BAR(); mm8(alo, blo, 0, 0); BAR(); \
    ldB2(P, bhi, 2); stA2((P) ^ 1, 1, (S) + 1); \
    BAR(); mm8(alo, bhi, 0, 2); BAR(); \
    ldA2(P, ahi, 2); stB2(P, 0, (S) + 2); \
    BAR(); mm8(ahi, bhi, 2, 2); BAR(); \
    stA2(P, 0, (S) + 2); \
    BAR(); mm8(ahi, blo, 2, 0); \
    asm volatile("s_waitcnt vmcnt(3)" ::: "memory"); \
    BAR(); \
  } while (0)

  // prologue: tile0 all halves (6 oldest), then tile1 {B0 x2, A0} (3 newest)
  stB2(0, 0, 0); stB2(0, 1, 0); stA2(0, 0, 0); stA2(0, 1, 0);
  stB2(1, 0, 1); stA2(1, 0, 1);
  asm volatile("s_waitcnt vmcnt(3)" ::: "memory");   // tile0 landed, 3 in flight
  BAR();

  const int NIT = KDIM / 64;   // 144
  for (int s = 0; s < NIT - 2; s += 2) {   // 142 steady tiles
    TILE_STEADY(s, 0);
    TILE_STEADY(s + 1, 1);
  }
  // s = 142 (P=0): stage only tile 143's B1/A1; drain at end
  ldA2(0, alo, 0); ldB2(0, blo, 0); stB2(1, 1, NIT - 1);
  BAR(); mm8(alo, blo, 0, 0); BAR();
  ldB2(0, bhi, 2); stA2(1, 1, NIT - 1);
  BAR(); mm8(alo, bhi, 0, 2); BAR();
  ldA2(0, ahi, 2);
  BAR(); mm8(ahi, bhi, 2, 2); BAR();
  BAR(); mm8(ahi, blo, 2, 0);
  asm volatile("s_waitcnt vmcnt(0)" ::: "memory");
  BAR();
  // s = 143 (P=1): compute only
  ldA2(1, alo, 0); ldB2(1, blo, 0);
  BAR(); mm8(alo, blo, 0, 0); BAR();
  ldB2(1, bhi, 2);
  BAR(); mm8(alo, bhi, 0, 2); BAR();
  ldA2(1, ahi, 2);
  BAR(); mm8(ahi, bhi, 2, 2); BAR();
  mm8(ahi, blo, 2, 0);
#undef TILE_STEADY
#undef BAR

  // epilogue: C/D layout col=lane&15, row=(lane>>4)*4+reg. Fused 1/12 + bias.
  int lg = l >> 4;
  const float sc = 1.f / 12.f;
#pragma unroll
  for (int m = 0; m < 4; m++)
#pragma unroll
    for (int n = 0; n < 4; n++) {
      int col = col0 + wc * 64 + n * 16 + lr;
      float bv = bias[col];
#pragma unroll
      for (int r = 0; r < 4; r++) {
        int row = row0 + wr * 64 + m * 16 + lg * 4 + r;
        if (row < NNODES)
          C[(size_t)row * FDIM + col] = acc[m][n][r] * sc + bv;
      }
    }
}

// ---------------- graph mean pool (batch is sorted) ----------------
__global__ void k_pool(const float* __restrict__ h2, const int* __restrict__ batch,
                       float* __restrict__ g) {
  int gi = blockIdx.x;
  int c = blockIdx.y * 256 + threadIdx.x;
  int lo = 0, hi = NNODES;
  while (lo < hi) { int mid = (lo + hi) >> 1; if (batch[mid] < gi) lo = mid + 1; else hi = mid; }
  int start = lo;
  lo = start; hi = NNODES;
  while (lo < hi) { int mid = (lo + hi) >> 1; if (batch[mid] < gi + 1) lo = mid + 1; else hi = mid; }
  int end = lo;
  int cnt = end - start; if (cnt < 1) cnt = 1;
  float inv = 1.f / (float)cnt;
  float s = 0.f;
  for (int n = start; n < end; n++) s += h2[(size_t)n * FDIM + c];
  g[gi * FDIM + c] = s * inv;
}

// ---------------- MLP head ----------------
__global__ void k_mlp(const float* __restrict__ g, const float* __restrict__ w1,
                      const float* __restrict__ b1, const float* __restrict__ w2,
                      const float* __restrict__ b2, float* __restrict__ out) {
  int gi = blockIdx.x;
  int t = threadIdx.x;  // 128
  __shared__ float gs[FDIM];
  __shared__ float zs[128];
  for (int i = t; i < FDIM; i += 128) gs[i] = g[gi * FDIM + i];
  __syncthreads();
  float a = b1[t];
  for (int k = 0; k < FDIM; k++) a += gs[k] * w1[k * 128 + t];
  zs[t] = (a > 0.f) ? a : 0.f;
  __syncthreads();
  if (t < 4) {
    float o = b2[t];
    for (int i = 0; i < 128; i++) o += zs[i] * w2[i * 4 + t];
    out[gi * 4 + t] = o;
  }
}

extern "C" void kernel_launch(void* const* d_in, const int* in_sizes, int n_in,
                              void* d_out, int out_size, void* d_ws, size_t ws_size,
                              hipStream_t stream) {
  const float* x    = (const float*)d_in[0];
  const int*   ei   = (const int*)d_in[1];
  const int*   batch= (const int*)d_in[2];
  const float* W1   = (const float*)d_in[3];
  const float* as1  = (const float*)d_in[4];
  const float* ad1  = (const float*)d_in[5];
  const float* b1   = (const float*)d_in[6];
  const float* W2   = (const float*)d_in[7];
  const float* as2  = (const float*)d_in[8];
  const float* ad2  = (const float*)d_in[9];
  const float* b2   = (const float*)d_in[10];
  const float* mw1  = (const float*)d_in[11];
  const float* mb1  = (const float*)d_in[12];
  const float* mw2  = (const float*)d_in[13];
  const float* mb2  = (const float*)d_in[14];
  float* out = (float*)d_out;
  (void)in_sizes; (void)n_in; (void)out_size; (void)ws_size;

  char* wsb = (char*)d_ws;
  size_t off = 0;
  auto alloc = [&](size_t bytes) -> void* {
    void* p = wsb + off;
    off += (bytes + 255) & ~(size_t)255;
    return p;
  };
  // ws: y 188.7 + Bt2 14.2 + h1 30.7 + h2 30.7 + small ≈ 265.8 MB (fits r0's budget).
  // y pad rows [10000,10240) zeroed once; k_agg writes only n<NNODES so pads
  // stay zero across both layers; k_gemm2 reads pads (zero), guards C stores.
  u16*  y      = (u16*)alloc((size_t)MPAD * KDIM * 2);     // 188.7 MB
  u16*  Bt2    = (u16*)alloc((size_t)FDIM * KDIM * 2);     // 14.2 MB
  float* h1    = (float*)alloc((size_t)NNODES * FDIM * 4); // 30.7 MB
  float* h2    = (float*)alloc((size_t)NNODES * FDIM * 4); // 30.7 MB
  float* sd    = (float*)alloc((size_t)NNODES * 24 * 4);
  float* Ut    = (float*)alloc((size_t)FDIM * 24 * 4);
  int*  counts = (int*)alloc((size_t)NNODES * 4);
  int*  offs   = (int*)alloc((size_t)(NNODES + 1) * 4);
  int*  cursor = (int*)alloc((size_t)NNODES * 4);
  int*  elist  = (int*)alloc((size_t)ETOT * 4);
  float* gbuf  = (float*)alloc((size_t)NGRAPH * FDIM * 4);

  // CSR by dst (edges identical for both layers)
  hipMemsetAsync(counts, 0, NNODES * 4, stream);
  hipMemsetAsync(y + (size_t)NNODES * KDIM, 0, (size_t)(MPAD - NNODES) * KDIM * 2, stream);
  k_count<<<(ETOT + 255) / 256, 256, 0, stream>>>(ei + NEDGES, counts);
  k_scan<<<1, 256, 0, stream>>>(counts, offs);
  k_seed<<<(NNODES + 255) / 256, 256, 0, stream>>>(offs, cursor);
  k_scatter<<<(ETOT + 255) / 256, 256, 0, stream>>>(ei + NEDGES, cursor, elist);

  for (int layer = 0; layer < 2; layer++) {
    const float* xin  = layer ? h1  : x;
    const float* W    = layer ? W2  : W1;
    const float* asrc = layer ? as2 : as1;
    const float* adst = layer ? ad2 : ad1;
    const float* bb   = layer ? b2  : b1;
    float* hout       = layer ? h2  : h1;

    k_U<<<FDIM, 256, 0, stream>>>(W, asrc, adst, Ut);
    k_sd<<<(NNODES + 19) / 20, 256, 0, stream>>>(xin, Ut, sd);
    k_trans2<<<dim3(FDIM / 32, KDIM / 32), dim3(32, 8), 0, stream>>>(W, Bt2);
    k_agg<<<(NNODES + 3) / 4, 256, 0, stream>>>(xin, ei, offs, elist, sd, y);
    k_gemm2<<<(MPAD / 128) * 3, 512, 0, stream>>>(y, Bt2, hout, bb);
  }

  k_pool<<<dim3(NGRAPH, 3), 256, 0, stream>>>(h2, batch, gbuf);
  k_mlp<<<NGRAPH, 128, 0, stream>>>(gbuf, mw1, mb1, mw2, mb2, out);
}